// Round 1
// baseline (25244.206 us; speedup 1.0000x reference)
//
#include <hip/hip_runtime.h>
#include <math.h>

#define LAYERS 8
#define C 384
#define NH 8
#define NE 4
#define TD 256
#define NV 256
#define WIN 64
#define MM 56
#define HD 48
#define BB 64
#define TT 256
#define NT (BB*TT)
#define N3C 1152
#define FF 1536
#define SCALE_QK 0.14433756729740643f

static __device__ __forceinline__ float wsum(float v){
#pragma unroll
  for(int o=32;o;o>>=1) v += __shfl_xor(v,o);
  return v;
}
static __device__ __forceinline__ float wmax(float v){
#pragma unroll
  for(int o=32;o;o>>=1) v = fmaxf(v,__shfl_xor(v,o));
  return v;
}

// x[b,t,:] = tok_emb[tokens[b,t]] + pos_emb[t]
__global__ void k_embed(const int* __restrict__ tokens, const float* __restrict__ tok_emb,
                        const float* __restrict__ pos_emb, float* __restrict__ x){
  int idx = blockIdx.x*256 + threadIdx.x;
  if (idx >= NT*C) return;
  int t = idx / C, c = idx - t*C;
  x[idx] = tok_emb[tokens[t]*C + c] + pos_emb[(t % TT)*C + c];
}

// wave-per-row layernorm over C=384
__global__ void k_ln(const float* __restrict__ in, const float* __restrict__ w,
                     const float* __restrict__ b, float* __restrict__ out){
  int row = blockIdx.x*4 + (threadIdx.x>>6);
  int lane = threadIdx.x & 63;
  const float* xr = in + (size_t)row*C;
  float v[6]; float s = 0.f;
#pragma unroll
  for(int i=0;i<6;i++){ v[i]=xr[lane+64*i]; s+=v[i]; }
  s = wsum(s);
  float mu = s*(1.f/C);
  float q=0.f;
#pragma unroll
  for(int i=0;i<6;i++){ float d=v[i]-mu; q+=d*d; }
  q = wsum(q);
  float inv = rsqrtf(q*(1.f/C)+1e-5f);
  float* orow = out + (size_t)row*C;
#pragma unroll
  for(int i=0;i<6;i++){ int c=lane+64*i; orow[c] = (v[i]-mu)*inv*w[c]+b[c]; }
}

// C = act(A@W + bias) [* rowscale] [+= accumulate]; A optionally column-scaled.
// 64x64 tile, BK=16, 256 threads, 4x4 per thread, fp32.
// ACT: 0 none, 1 tanh, 2 exact gelu
template<int ACT, bool COLSCALE, bool ROWSCALE, bool ACCUM>
__global__ __launch_bounds__(256) void k_gemm(const float* __restrict__ A,
    const float* __restrict__ W, const float* __restrict__ bias,
    const float* __restrict__ colscale, const float* __restrict__ rowscale,
    float* __restrict__ Cout, int Mn, int Nn, int Kn){
  __shared__ __attribute__((aligned(16))) float As[16][68]; // As[k][m] (transposed)
  __shared__ __attribute__((aligned(16))) float Bs[16][68]; // Bs[k][n]
  int bm = blockIdx.y*64, bn = blockIdx.x*64;
  int tid = threadIdx.x;
  int tx = tid & 15, ty = tid >> 4;
  int ar = tid >> 2, ac4 = (tid & 3)*4;
  int br = tid >> 4, bc4 = (tid & 15)*4;
  float acc[4][4] = {};
  for(int k0=0;k0<Kn;k0+=16){
    float4 av = *(const float4*)(A + (size_t)(bm+ar)*Kn + k0 + ac4);
    if (COLSCALE){
      av.x *= colscale[k0+ac4+0]; av.y *= colscale[k0+ac4+1];
      av.z *= colscale[k0+ac4+2]; av.w *= colscale[k0+ac4+3];
    }
    As[ac4+0][ar]=av.x; As[ac4+1][ar]=av.y; As[ac4+2][ar]=av.z; As[ac4+3][ar]=av.w;
    float4 bv = *(const float4*)(W + (size_t)(k0+br)*Nn + bn + bc4);
    *(float4*)&Bs[br][bc4] = bv;
    __syncthreads();
#pragma unroll
    for(int kk=0;kk<16;kk++){
      float4 a4 = *(const float4*)&As[kk][ty*4];
      float4 b4 = *(const float4*)&Bs[kk][tx*4];
      float a[4] = {a4.x,a4.y,a4.z,a4.w};
      float b[4] = {b4.x,b4.y,b4.z,b4.w};
#pragma unroll
      for(int i=0;i<4;i++)
#pragma unroll
        for(int j=0;j<4;j++) acc[i][j] += a[i]*b[j];
    }
    __syncthreads();
  }
#pragma unroll
  for(int i=0;i<4;i++){
    int row = bm + ty*4 + i;
    float rs = 1.f;
    if (ROWSCALE) rs = rowscale[(size_t)row*NE];
#pragma unroll
    for(int j=0;j<4;j++){
      int col = bn + tx*4 + j;
      float val = acc[i][j] + bias[col];
      if (ACT==1) val = tanhf(val);
      if (ACT==2) val = 0.5f*val*(1.f+erff(val*0.70710678118654752f));
      if (ROWSCALE) val *= rs;
      float* p = Cout + (size_t)row*Nn + col;
      if (ACCUM) *p += val; else *p = val;
    }
  }
}

// attention: one block per (b, head). K/V (mem-prefixed) staged in LDS fp32.
__global__ __launch_bounds__(256) void k_attn(const float* __restrict__ qkv,
    const float* __restrict__ mem, float* __restrict__ y){
  __shared__ float ks[MM+TT][HD];
  __shared__ float vs[MM+TT][HD];
  __shared__ float att[4][MM+TT];
  int b = blockIdx.x >> 3, hh = blockIdx.x & 7;
  int tid = threadIdx.x;
  for(int idx=tid; idx<(MM+TT)*HD; idx+=256){
    int j = idx/HD, d = idx - j*HD;
    float kv, vv;
    if (j < MM){ kv = mem[j*C + hh*HD + d]; vv = kv; }
    else {
      const float* row = qkv + (size_t)(b*TT + j - MM)*N3C;
      kv = row[C + hh*HD + d]; vv = row[2*C + hh*HD + d];
    }
    ks[j][d]=kv; vs[j][d]=vv;
  }
  __syncthreads();
  int wave = tid>>6, lane = tid&63;
  for(int i=wave;i<TT;i+=4){
    const float* qrow = qkv + (size_t)(b*TT+i)*N3C + hh*HD;
    float qreg[HD];
#pragma unroll
    for(int d=0;d<HD;d++) qreg[d]=qrow[d];
    float sc[5]; float mx = -1e30f;
#pragma unroll
    for(int jj=0;jj<5;jj++){
      int j = lane + jj*64;
      bool valid = (j < MM) || (j < MM+TT && (j-MM) <= i && (i-(j-MM)) <= WIN);
      float s = -1e30f;
      if (valid){
        float dot=0.f;
#pragma unroll
        for(int d=0;d<HD;d++) dot += qreg[d]*ks[j][d];
        s = dot*SCALE_QK;
      }
      sc[jj]=s; mx = fmaxf(mx,s);
    }
    mx = wmax(mx);
    float ls=0.f;
#pragma unroll
    for(int jj=0;jj<5;jj++){
      float p = (sc[jj] > -1e29f) ? expf(sc[jj]-mx) : 0.f;
      ls += p;
      int j = lane + jj*64;
      if (j < MM+TT) att[wave][j] = p;
    }
    ls = wsum(ls);
    float inv = 1.f/ls;
    if (lane < HD){
      float acc=0.f;
      for(int j=0;j<MM;j++) acc += att[wave][j]*vs[j][lane];
      int lo = MM + (i>WIN ? i-WIN : 0), hi = MM + i;
      for(int j=lo;j<=hi;j++) acc += att[wave][j]*vs[j][lane];
      y[(size_t)(b*TT+i)*C + hh*HD + lane] = acc*inv;
    }
  }
}

// router: wave per token; softmax over E=4, top-2, renormalize
__global__ void k_gate(const float* __restrict__ h2, const float* __restrict__ gw,
                       const float* __restrict__ gb, float* __restrict__ wout){
  int row = blockIdx.x*4 + (threadIdx.x>>6);
  int lane = threadIdx.x & 63;
  const float* hr = h2 + (size_t)row*C;
  float a0=0,a1=0,a2=0,a3=0;
  for(int c=lane;c<C;c+=64){
    float hv = hr[c];
    const float* g = gw + c*NE;
    a0+=hv*g[0]; a1+=hv*g[1]; a2+=hv*g[2]; a3+=hv*g[3];
  }
  a0=wsum(a0); a1=wsum(a1); a2=wsum(a2); a3=wsum(a3);
  if (lane==0){
    float p[4]={a0+gb[0],a1+gb[1],a2+gb[2],a3+gb[3]};
    float m = fmaxf(fmaxf(p[0],p[1]),fmaxf(p[2],p[3]));
    float s=0.f;
#pragma unroll
    for(int e=0;e<4;e++){ p[e]=expf(p[e]-m); s+=p[e]; }
#pragma unroll
    for(int e=0;e<4;e++) p[e] /= s;
    int i1=0;
    for(int e=1;e<4;e++) if(p[e]>p[i1]) i1=e;
    int i2=-1;
    for(int e=0;e<4;e++){ if(e==i1) continue; if(i2<0 || p[e]>p[i2]) i2=e; }
    float invs = 1.f/(p[i1]+p[i2]+1e-9f);
    float wv[4]={0.f,0.f,0.f,0.f};
    wv[i1]=p[i1]*invs; wv[i2]=p[i2]*invs;
    float* o = wout + (size_t)row*NE;
    o[0]=wv[0]; o[1]=wv[1]; o[2]=wv[2]; o[3]=wv[3];
  }
}

extern "C" void kernel_launch(void* const* d_in, const int* in_sizes, int n_in,
                              void* d_out, int out_size, void* d_ws, size_t ws_size,
                              hipStream_t stream){
  (void)in_sizes; (void)n_in; (void)out_size; (void)ws_size;
  const int*   tokens  = (const int*)d_in[0];
  const float* tok_emb = (const float*)d_in[1];
  const float* pos_emb = (const float*)d_in[2];
  const float* mem     = (const float*)d_in[3];
  const float* ln1_w   = (const float*)d_in[4];
  const float* ln1_b   = (const float*)d_in[5];
  const float* qkv_w   = (const float*)d_in[6];
  const float* qkv_b   = (const float*)d_in[7];
  const float* proj_w  = (const float*)d_in[8];
  const float* proj_b  = (const float*)d_in[9];
  const float* attn_g  = (const float*)d_in[10];
  const float* th1_w   = (const float*)d_in[11];
  const float* th1_b   = (const float*)d_in[12];
  const float* th2_w   = (const float*)d_in[13];
  const float* th2_b   = (const float*)d_in[14];
  const float* ln2_w   = (const float*)d_in[15];
  const float* ln2_b   = (const float*)d_in[16];
  const float* gate_w  = (const float*)d_in[17];
  const float* gate_b  = (const float*)d_in[18];
  const float* e1_w    = (const float*)d_in[19];
  const float* e1_b    = (const float*)d_in[20];
  const float* e2_w    = (const float*)d_in[21];
  const float* e2_b    = (const float*)d_in[22];
  const float* lnf_w   = (const float*)d_in[23];
  const float* lnf_b   = (const float*)d_in[24];
  const float* head_w  = (const float*)d_in[25];
  const float* head_b  = (const float*)d_in[26];
  float* out = (float*)d_out;

  float* ws   = (float*)d_ws;
  float* x    = ws;                       // NT*C
  float* h    = x + (size_t)NT*C;         // NT*C   (ln1 out / ln2 out / lnf out)
  float* y    = h + (size_t)NT*C;         // NT*C   (attn out; aliased as t1)
  float* big  = y + (size_t)NT*C;         // NT*FF  (qkv: NT*1152 / he: NT*1536)
  float* wbuf = big + (size_t)NT*FF;      // NT*NE  (router weights)
  float* t1   = y;                        // NT*TD <= NT*C

  dim3 b256(256);
  k_embed<<<dim3((NT*C+255)/256), b256, 0, stream>>>(tokens, tok_emb, pos_emb, x);
  for(int l=0;l<LAYERS;l++){
    k_ln<<<dim3(NT/4), b256, 0, stream>>>(x, ln1_w+l*C, ln1_b+l*C, h);
    k_gemm<0,false,false,false><<<dim3(N3C/64, NT/64), b256, 0, stream>>>(
        h, qkv_w+(size_t)l*C*N3C, qkv_b+(size_t)l*N3C, nullptr, nullptr, big, NT, N3C, C);
    k_attn<<<dim3(BB*NH), b256, 0, stream>>>(big, mem, y);
    k_gemm<0,true,false,true><<<dim3(C/64, NT/64), b256, 0, stream>>>(
        y, proj_w+(size_t)l*C*C, proj_b+(size_t)l*C, attn_g+l*C, nullptr, x, NT, C, C);
    k_gemm<1,false,false,false><<<dim3(TD/64, NT/64), b256, 0, stream>>>(
        x, th1_w+(size_t)l*C*TD, th1_b+(size_t)l*TD, nullptr, nullptr, t1, NT, TD, C);
    k_gemm<0,false,false,true><<<dim3(C/64, NT/64), b256, 0, stream>>>(
        t1, th2_w+(size_t)l*TD*C, th2_b+(size_t)l*C, nullptr, nullptr, x, NT, C, TD);
    k_ln<<<dim3(NT/4), b256, 0, stream>>>(x, ln2_w+l*C, ln2_b+l*C, h);
    k_gate<<<dim3(NT/4), b256, 0, stream>>>(h, gate_w+(size_t)l*C*NE, gate_b+(size_t)l*NE, wbuf);
    for(int e=0;e<NE;e++){
      k_gemm<2,false,false,false><<<dim3(FF/64, NT/64), b256, 0, stream>>>(
          h, e1_w+((size_t)(l*NE+e))*C*FF, e1_b+(size_t)(l*NE+e)*FF, nullptr, nullptr, big, NT, FF, C);
      k_gemm<0,false,true,true><<<dim3(C/64, NT/64), b256, 0, stream>>>(
          big, e2_w+((size_t)(l*NE+e))*FF*C, e2_b+(size_t)(l*NE+e)*C, nullptr, wbuf+e, x, NT, C, FF);
    }
  }
  k_ln<<<dim3(NT/4), b256, 0, stream>>>(x, lnf_w, lnf_b, h);
  k_gemm<0,false,false,false><<<dim3(NV/64, NT/64), b256, 0, stream>>>(
      h, head_w, head_b, nullptr, nullptr, out, NT, NV, C);
}